// Round 8
// baseline (251.777 us; speedup 1.0000x reference)
//
#include <hip/hip_runtime.h>
#include <hip/hip_bf16.h>

#define NB    2
#define NK    2048
#define NPTS  16384
#define NBK   4096            // NB*NK
#define MSAMP 65536.0f        // NBK*16 samples per scale for BN0/BN1
#define MROW  4096.0f         // rows for final BN

#define NXB   88              // x bins (140 / 1.6)
#define NYB   50              // y bins (80 / 1.6)
#define NBIN  4400            // NXB*NYB
#define BSTRIDE 4416          // padded per-batch bin stride (incl. sentinel)

__device__ __forceinline__ void binof(float x, float y, int& bx, int& by) {
  bx = min(NXB - 1, max(0, (int)floorf((x + 70.f) * 0.625f)));
  by = min(NYB - 1, max(0, (int)floorf((y + 40.f) * 0.625f)));
}

// insert (v=orig idx, p=payload) into ascending-by-idx 16-slot list
__device__ __forceinline__ void insert16(int v, int p, int* li, int* lp) {
#pragma unroll
  for (int k = 0; k < 16; k++) {
    const bool ins = v < li[k];
    const int tv = li[k], tp = lp[k];
    li[k] = ins ? v : tv;
    lp[k] = ins ? p : tp;
    v = ins ? tv : v;
    p = ins ? tp : p;
  }
}

// ---------------------------------------------------------------------------
// A: prep. Blocks 0..1: per-batch bin histogram + scan + scatter (r5 logic,
// fused into one block per batch via LDS fill counters). Blocks 2..513: BEV
// plane-per-(batch,channel) — stage 70KB plane in LDS (coalesced, image read
// once), interpolate 2048 keypoints from LDS.
// ---------------------------------------------------------------------------
__global__ __launch_bounds__(256) void prep_kernel(
    const float* __restrict__ kp, const float* __restrict__ pts,
    const float* __restrict__ pfeat, const float* __restrict__ bev,
    const int* __restrict__ stridep,
    int* __restrict__ bin_start, float4* __restrict__ sorted,
    int* __restrict__ sidx, float* __restrict__ feats)
{
  __shared__ __align__(16) char smem[70400];
  const int t = threadIdx.x;

  if (blockIdx.x < 2) {
    // ---- BINS role ----
    int* hist  = (int*)smem;                   // 4400 ints
    int* wpart = (int*)(smem + 70400 - 16);    // 4 ints
    const int b = blockIdx.x;
    for (int i = t; i < NBIN; i += 256) hist[i] = 0;
    __syncthreads();
    const float* px = pts   + (size_t)b * NPTS * 3;
    const float* pf = pfeat + (size_t)b * NPTS;
    // histogram (4-way unrolled for MLP-level latency hiding)
    for (int i = t; i < NPTS; i += 1024) {
      #pragma unroll
      for (int u = 0; u < 4; u++) {
        const int j = i + u * 256;
        const float x = px[j*3+0], y = px[j*3+1];
        int bx, by; binof(x, y, bx, by);
        atomicAdd(&hist[by * NXB + bx], 1);
      }
    }
    __syncthreads();
    // chunked exclusive scan: 256 threads x 18 bins (r5-verified)
    const int lo = t * 18, hi = min(NBIN, lo + 18);
    int s = 0;
    for (int i = lo; i < hi; i++) s += hist[i];
    const int lane = t & 63, wave = t >> 6;
    int x = s;
    #pragma unroll
    for (int d = 1; d < 64; d <<= 1) {
      const int y = __shfl_up(x, d);
      if (lane >= d) x += y;
    }
    if (lane == 63) wpart[wave] = x;
    __syncthreads();
    int base = 0;
    for (int wv = 0; wv < wave; wv++) base += wpart[wv];
    int run = base + x - s;                 // exclusive prefix of this chunk
    const int bb = b * BSTRIDE;
    for (int i = lo; i < hi; i++) {
      const int h = hist[i];
      bin_start[bb + i] = run;
      hist[i] = run;                        // becomes LDS fill counter
      run += h;
    }
    if (t == 0) bin_start[bb + NBIN] = NPTS;   // sentinel
    __syncthreads();
    // scatter using LDS fill counters
    const int b2 = b * NPTS;
    for (int i = t; i < NPTS; i += 1024) {
      #pragma unroll
      for (int u = 0; u < 4; u++) {
        const int j = i + u * 256;
        const float x2 = px[j*3+0], y2 = px[j*3+1], z2 = px[j*3+2];
        const float f = pf[j];
        int bx, by; binof(x2, y2, bx, by);
        const int pos = atomicAdd(&hist[by * NXB + bx], 1);
        sorted[b2 + pos] = make_float4(x2, y2, z2, f);
        sidx[b2 + pos] = j;
      }
    }
    return;
  }

  // ---- BEV role ----
  {
    const int pb = blockIdx.x - 2;       // 0..511
    const int b  = pb >> 8;
    const int c  = pb & 255;
    float4* plane4 = (float4*)smem;
    const float4* src = (const float4*)(bev + ((size_t)(b * 256 + c)) * 17600);
    for (int i = t; i < 4400; i += 256) plane4[i] = src[i];
    const float st = (float)(*stridep);
    __syncthreads();
    const float* plane = (const float*)smem;
    for (int k = t; k < 2048; k += 256) {
      const int bk = b * 2048 + k;
      const float xx = (kp[bk*3+0] - (-70.4f)) / 0.1f / st;
      const float yy = (kp[bk*3+1] - (-40.0f)) / 0.1f / st;
      const int xf = (int)floorf(xx), yf = (int)floorf(yy);
      const int x0 = min(max(xf, 0), 175), x1 = min(max(xf + 1, 0), 175);
      const int y0 = min(max(yf, 0), 99),  y1 = min(max(yf + 1, 0), 99);
      const float x0f = (float)x0, x1f = (float)x1, y0f = (float)y0, y1f = (float)y1;
      const float wa = (x1f - xx) * (y1f - yy);
      const float wb = (x1f - xx) * (yy - y0f);
      const float wc = (xx - x0f) * (y1f - yy);
      const float wd = (xx - x0f) * (yy - y0f);
      const float Ia = plane[y0 * 176 + x0];
      const float Ib = plane[y1 * 176 + x0];
      const float Ic = plane[y0 * 176 + x1];
      const float Id = plane[y1 * 176 + x1];
      feats[(size_t)bk * 304 + c] = Ia * wa + Ib * wb + Ic * wc + Id * wd;
    }
  }
}

// ---------------------------------------------------------------------------
// B: binned ball query. 1 thread per keypoint (64 blocks x 64). r6-verified.
// ---------------------------------------------------------------------------
__global__ __launch_bounds__(64) void query_kernel(
    const float* __restrict__ kp, const int* __restrict__ bin_start,
    const float4* __restrict__ sorted, const int* __restrict__ sidx,
    float* __restrict__ g0buf, float* __restrict__ g1buf,
    int* __restrict__ cnt, float* __restrict__ part0)
{
  const int t = threadIdx.x;
  const int bk = blockIdx.x * 64 + t;      // 0..4095
  const int b = bk >> 11;
  const float kx = kp[bk*3+0], ky = kp[bk*3+1], kz = kp[bk*3+2];
  const int bb = b * BSTRIDE;
  const int b2 = b * NPTS;

  int li0[16], lp0[16], li1[16], lp1[16];
  #pragma unroll
  for (int k = 0; k < 16; k++) { li0[k] = 0x7fffffff; li1[k] = 0x7fffffff; lp0[k] = 0; lp1[k] = 0; }
  int c0 = 0, c1 = 0;

  const int bx0 = max(0,       (int)floorf((kx - 0.801f + 70.f) * 0.625f));
  const int bx1 = min(NXB - 1, (int)floorf((kx + 0.801f + 70.f) * 0.625f));
  const int by0 = max(0,       (int)floorf((ky - 0.801f + 40.f) * 0.625f));
  const int by1 = min(NYB - 1, (int)floorf((ky + 0.801f + 40.f) * 0.625f));

  for (int by = by0; by <= by1; by++) {
    for (int bx = bx0; bx <= bx1; bx++) {
      const int bin = by * NXB + bx;
      const int s = bin_start[bb + bin];
      const int e = bin_start[bb + bin + 1];
      for (int p = s; p < e; p++) {
        const float4 P = sorted[b2 + p];
        const float dx = P.x - kx, dy = P.y - ky, dz = P.z - kz;
        const float d2 = dx*dx + dy*dy + dz*dz;
        if (d2 < 0.64f) {
          const int oi = sidx[b2 + p];
          insert16(oi, p, li1, lp1); c1++;
          if (d2 < 0.16f) { insert16(oi, p, li0, lp0); c0++; }
        }
      }
    }
  }

  float m0[14], m1[14];
  #pragma unroll
  for (int i = 0; i < 14; i++) { m0[i] = 0.f; m1[i] = 0.f; }

  {
    const int n0 = min(c0, 16);
    float s0x = 0.f, s0y = 0.f, s0z = 0.f, s0f = 0.f;
    float4* gout = (float4*)(g0buf + (size_t)bk * 64);
    #pragma unroll
    for (int k = 0; k < 16; k++) {
      float dx, dy, dz, ff;
      if (k < n0) {
        const float4 P = sorted[b2 + lp0[k]];
        dx = P.x - kx; dy = P.y - ky; dz = P.z - kz; ff = P.w;
      } else {
        dx = s0x; dy = s0y; dz = s0z; ff = s0f;
      }
      if (k == 0 && n0 > 0) { s0x = dx; s0y = dy; s0z = dz; s0f = ff; }
      gout[k] = make_float4(dx, dy, dz, ff);
      m0[0] += dx; m0[1] += dy; m0[2] += dz; m0[3] += ff;
      m0[4] += dx*dx; m0[5] += dx*dy; m0[6] += dx*dz; m0[7] += dx*ff;
      m0[8] += dy*dy; m0[9] += dy*dz; m0[10] += dy*ff;
      m0[11] += dz*dz; m0[12] += dz*ff; m0[13] += ff*ff;
    }
  }
  {
    const int n1 = min(c1, 16);
    float s0x = 0.f, s0y = 0.f, s0z = 0.f, s0f = 0.f;
    float4* gout = (float4*)(g1buf + (size_t)bk * 64);
    #pragma unroll
    for (int k = 0; k < 16; k++) {
      float dx, dy, dz, ff;
      if (k < n1) {
        const float4 P = sorted[b2 + lp1[k]];
        dx = P.x - kx; dy = P.y - ky; dz = P.z - kz; ff = P.w;
      } else {
        dx = s0x; dy = s0y; dz = s0z; ff = s0f;
      }
      if (k == 0 && n1 > 0) { s0x = dx; s0y = dy; s0z = dz; s0f = ff; }
      gout[k] = make_float4(dx, dy, dz, ff);
      m1[0] += dx; m1[1] += dy; m1[2] += dz; m1[3] += ff;
      m1[4] += dx*dx; m1[5] += dx*dy; m1[6] += dx*dz; m1[7] += dx*ff;
      m1[8] += dy*dy; m1[9] += dy*dz; m1[10] += dy*ff;
      m1[11] += dz*dz; m1[12] += dz*ff; m1[13] += ff*ff;
    }
  }
  cnt[bk] = c0;
  cnt[NBK + bk] = c1;

  float mm[28];
  #pragma unroll
  for (int i = 0; i < 14; i++) { mm[i] = m0[i]; mm[14 + i] = m1[i]; }
  #pragma unroll
  for (int d = 1; d < 64; d <<= 1) {
    #pragma unroll
    for (int i = 0; i < 28; i++) mm[i] += __shfl_xor(mm[i], d);
  }
  if (t == 0) {
    #pragma unroll
    for (int i = 0; i < 28; i++) part0[blockIdx.x * 28 + i] = mm[i];
  }
}

// ---------------------------------------------------------------------------
// helper: compute BN0 params (sP[0:64]) from S0[28] sums — runs in-block
// ---------------------------------------------------------------------------
__device__ __forceinline__ void bn0_params(
    int t, const float* S0, const float* sW0a, const float* sW0b,
    const float* gm0s0, const float* bt0s0,
    const float* gm0s1, const float* bt0s1, float* sP)
{
  if (t < 32) {
    const int s = t >> 4, c = t & 15;
    const float* W  = s ? sW0b : sW0a;
    const float* G  = s ? gm0s1 : gm0s0;
    const float* Bt = s ? bt0s1 : bt0s0;
    const float* Sx = S0 + s * 14;
    const float w0 = W[c*4+0], w1 = W[c*4+1];
    const float w2 = W[c*4+2], w3 = W[c*4+3];
    const float inv = 1.0f / MSAMP;
    const float mean = (w0*Sx[0] + w1*Sx[1] + w2*Sx[2] + w3*Sx[3]) * inv;
    float e2 = w0*w0*Sx[4] + 2.f*w0*w1*Sx[5] + 2.f*w0*w2*Sx[6] + 2.f*w0*w3*Sx[7]
             + w1*w1*Sx[8] + 2.f*w1*w2*Sx[9] + 2.f*w1*w3*Sx[10]
             + w2*w2*Sx[11] + 2.f*w2*w3*Sx[12] + w3*w3*Sx[13];
    e2 *= inv;
    const float var = e2 - mean * mean;
    const float A = G[c] / sqrtf(var + 1e-5f);
    sP[s*32 + c]      = A;
    sP[s*32 + 16 + c] = Bt[c] - mean * A;
  }
}

// ---------------------------------------------------------------------------
// C: BN1 stats (local BN0 finalize + per-slot MLP layer01 + sum/sumsq).
// grid 256 x 256. part1[block][96]. part0 has 64 rows.
// ---------------------------------------------------------------------------
__global__ __launch_bounds__(256) void stats1_kernel(
    const float* __restrict__ g0buf, const float* __restrict__ g1buf,
    const float* __restrict__ part0,
    const float* __restrict__ W0s0, const float* __restrict__ gm0s0, const float* __restrict__ bt0s0,
    const float* __restrict__ W0s1, const float* __restrict__ gm0s1, const float* __restrict__ bt0s1,
    const float* __restrict__ W1s0, const float* __restrict__ W1s1,
    float* __restrict__ part1)
{
  __shared__ float sW0a[64], sW0b[64], sW1a[256], sW1b[512], sP[64];
  __shared__ float tmp0[8][28], S0[28];
  __shared__ float red[16][96];
  const int t = threadIdx.x;
  if (t < 64) { sW0a[t] = W0s0[t]; sW0b[t] = W0s1[t]; }
  sW1a[t]       = W1s0[t];
  sW1b[t]       = W1s1[t];
  sW1b[t + 256] = W1s1[t + 256];
  for (int i = t; i < 16 * 96; i += 256) ((float*)red)[i] = 0.f;
  // local finalize0: sum part0[64][28]
  if (t < 224) {
    const int seg = t / 28, col = t % 28;
    float s = 0.f;
    for (int r = seg * 8; r < seg * 8 + 8; r++) s += part0[r * 28 + col];
    tmp0[seg][col] = s;
  }
  __syncthreads();
  if (t < 28) {
    float s = 0.f;
    #pragma unroll
    for (int g = 0; g < 8; g++) s += tmp0[g][t];
    S0[t] = s;
  }
  __syncthreads();
  bn0_params(t, S0, sW0a, sW0b, gm0s0, bt0s0, gm0s1, bt0s1, sP);
  __syncthreads();

  const int slot = blockIdx.x * 256 + t;
  const int wave = t >> 6, lane = t & 63;
  const int grp  = (wave << 2) | (lane >> 4);
  const bool leader = (lane & 15) == 0;

  float a1[16];
  {  // scale 0
    const float4 x = *(const float4*)(g0buf + (size_t)slot * 4);
    #pragma unroll
    for (int c = 0; c < 16; c++) {
      const float h = sW0a[c*4+0]*x.x + sW0a[c*4+1]*x.y + sW0a[c*4+2]*x.z + sW0a[c*4+3]*x.w;
      a1[c] = fmaxf(fmaf(sP[c], h, sP[16+c]), 0.f);
    }
    #pragma unroll
    for (int o = 0; o < 16; o++) {
      float h2 = 0.f;
      #pragma unroll
      for (int c = 0; c < 16; c++) h2 = fmaf(sW1a[o*16+c], a1[c], h2);
      float s = h2, q = h2 * h2;
      #pragma unroll
      for (int d = 1; d < 16; d <<= 1) { s += __shfl_xor(s, d); q += __shfl_xor(q, d); }
      if (leader) { red[grp][o] += s; red[grp][16+o] += q; }
    }
  }
  {  // scale 1
    const float4 x = *(const float4*)(g1buf + (size_t)slot * 4);
    #pragma unroll
    for (int c = 0; c < 16; c++) {
      const float h = sW0b[c*4+0]*x.x + sW0b[c*4+1]*x.y + sW0b[c*4+2]*x.z + sW0b[c*4+3]*x.w;
      a1[c] = fmaxf(fmaf(sP[32+c], h, sP[48+c]), 0.f);
    }
    #pragma unroll
    for (int o = 0; o < 32; o++) {
      float h2 = 0.f;
      #pragma unroll
      for (int c = 0; c < 16; c++) h2 = fmaf(sW1b[o*16+c], a1[c], h2);
      float s = h2, q = h2 * h2;
      #pragma unroll
      for (int d = 1; d < 16; d <<= 1) { s += __shfl_xor(s, d); q += __shfl_xor(q, d); }
      if (leader) { red[grp][32+o] += s; red[grp][64+o] += q; }
    }
  }
  __syncthreads();
  if (t < 96) {
    float s = 0.f;
    #pragma unroll
    for (int g = 0; g < 16; g++) s += red[g][t];
    part1[blockIdx.x * 96 + t] = s;
  }
}

// ---------------------------------------------------------------------------
// D: pool + fused GEMM. grid 256 x 256, 16 keypoints(rows)/block.
// Pool writes its 48 cols into the GEMM LDS tile; bev cols loaded from feats.
// ---------------------------------------------------------------------------
__global__ __launch_bounds__(256) void poolgemm_kernel(
    const float* __restrict__ g0buf, const float* __restrict__ g1buf,
    const int* __restrict__ cnt,
    const float* __restrict__ part0, const float* __restrict__ part1,
    const float* __restrict__ W0s0, const float* __restrict__ gm0s0, const float* __restrict__ bt0s0,
    const float* __restrict__ W0s1, const float* __restrict__ gm0s1, const float* __restrict__ bt0s1,
    const float* __restrict__ W1s0, const float* __restrict__ gm1s0, const float* __restrict__ bt1s0,
    const float* __restrict__ W1s1, const float* __restrict__ gm1s1, const float* __restrict__ bt1s1,
    const float* __restrict__ feats, const float* __restrict__ Wf,
    float* __restrict__ fused, float* __restrict__ part2)
{
  __shared__ float sW0a[64], sW0b[64], sW1a[256], sW1b[512], sP[160];
  __shared__ float tmp0[8][28], S0[28];
  __shared__ float tmp1[2][96], S1[96];
  __shared__ __align__(16) float sF[16 * 304];
  const int t = threadIdx.x;
  const int bk0 = blockIdx.x * 16;

  // start bev-column loads early (independent of params)
  for (int i = t; i < 4096; i += 256) {
    const int row = i >> 8, col = i & 255;
    sF[row * 304 + col] = feats[(size_t)(bk0 + row) * 304 + col];
  }
  if (t < 64)  { sW0a[t] = W0s0[t]; sW0b[t] = W0s1[t]; }
  sW1a[t]       = W1s0[t];
  sW1b[t]       = W1s1[t];
  sW1b[t + 256] = W1s1[t + 256];
  // local finalize0 (part0: 64 rows)
  if (t < 224) {
    const int seg = t / 28, col = t % 28;
    float s = 0.f;
    for (int r = seg * 8; r < seg * 8 + 8; r++) s += part0[r * 28 + col];
    tmp0[seg][col] = s;
  }
  __syncthreads();
  if (t < 28) {
    float s = 0.f;
    #pragma unroll
    for (int g = 0; g < 8; g++) s += tmp0[g][t];
    S0[t] = s;
  }
  // local finalize1 sums (part1: 256 rows x 96)
  if (t >= 32 && t < 224) {
    const int tt = t - 32;
    const int seg = tt / 96, col = tt % 96;
    float s = 0.f;
    for (int r = seg * 128; r < seg * 128 + 128; r++) s += part1[r * 96 + col];
    tmp1[seg][col] = s;
  }
  __syncthreads();
  bn0_params(t, S0, sW0a, sW0b, gm0s0, bt0s0, gm0s1, bt0s1, sP);
  if (t >= 64 && t < 160) {
    const int c = t - 64;
    S1[c] = tmp1[0][c] + tmp1[1][c];
  }
  __syncthreads();
  if (t < 48) {
    float sum, sq, G, Bv; int oA, oB;
    if (t < 16) { sum = S1[t];    sq = S1[16+t]; G = gm1s0[t]; Bv = bt1s0[t]; oA = 64+t;  oB = 80+t; }
    else { const int c = t - 16; sum = S1[32+c]; sq = S1[64+c]; G = gm1s1[c]; Bv = bt1s1[c]; oA = 96+c; oB = 128+c; }
    const float mean = sum / MSAMP;
    const float var  = sq / MSAMP - mean * mean;
    const float A = G / sqrtf(var + 1e-5f);
    sP[oA] = A;
    sP[oB] = Bv - mean * A;
  }
  __syncthreads();

  // ---- pool phase: 16 kp x 16 slots ----
  {
    const int lkp = t >> 4, slot = t & 15;
    const int bk = bk0 + lkp;
    const size_t si = (size_t)bk * 16 + slot;
    float a1[16], a2s0[16], a2s1[32];
    {
      const float4 x = *(const float4*)(g0buf + si * 4);
      #pragma unroll
      for (int c = 0; c < 16; c++) {
        const float h = sW0a[c*4+0]*x.x + sW0a[c*4+1]*x.y + sW0a[c*4+2]*x.z + sW0a[c*4+3]*x.w;
        a1[c] = fmaxf(fmaf(sP[c], h, sP[16+c]), 0.f);
      }
      #pragma unroll
      for (int o = 0; o < 16; o++) {
        float h2 = 0.f;
        #pragma unroll
        for (int c = 0; c < 16; c++) h2 = fmaf(sW1a[o*16+c], a1[c], h2);
        a2s0[o] = fmaxf(fmaf(sP[64+o], h2, sP[80+o]), 0.f);
      }
    }
    {
      const float4 x = *(const float4*)(g1buf + si * 4);
      #pragma unroll
      for (int c = 0; c < 16; c++) {
        const float h = sW0b[c*4+0]*x.x + sW0b[c*4+1]*x.y + sW0b[c*4+2]*x.z + sW0b[c*4+3]*x.w;
        a1[c] = fmaxf(fmaf(sP[32+c], h, sP[48+c]), 0.f);
      }
      #pragma unroll
      for (int o = 0; o < 32; o++) {
        float h2 = 0.f;
        #pragma unroll
        for (int c = 0; c < 16; c++) h2 = fmaf(sW1b[o*16+c], a1[c], h2);
        a2s1[o] = fmaxf(fmaf(sP[96+o], h2, sP[128+o]), 0.f);
      }
    }
    #pragma unroll
    for (int d = 1; d < 16; d <<= 1) {
      #pragma unroll
      for (int o = 0; o < 16; o++) a2s0[o] = fmaxf(a2s0[o], __shfl_xor(a2s0[o], d));
      #pragma unroll
      for (int o = 0; o < 32; o++) a2s1[o] = fmaxf(a2s1[o], __shfl_xor(a2s1[o], d));
    }
    if (slot == 0) {
      const int c0 = cnt[bk], c1 = cnt[NBK + bk];
      float* outp = sF + lkp * 304 + 256;
      #pragma unroll
      for (int o = 0; o < 16; o++) outp[o] = c0 ? a2s0[o] : 0.f;
      #pragma unroll
      for (int o = 0; o < 32; o++) outp[16 + o] = c1 ? a2s1[o] : 0.f;
    }
  }
  __syncthreads();

  // ---- GEMM phase: col c = t&127, rows rbase..rbase+8 ----
  {
    const int c = t & 127;
    const int rbase = (t >> 7) * 8;
    float acc[8];
    #pragma unroll
    for (int r = 0; r < 8; r++) acc[r] = 0.f;
    const float* wrow = Wf + (size_t)c * 304;
    for (int j4 = 0; j4 < 76; j4++) {
      const float4 w = *(const float4*)(wrow + j4 * 4);
      #pragma unroll
      for (int r = 0; r < 8; r++) {
        const float4 f = *(const float4*)(sF + (rbase + r) * 304 + j4 * 4);
        acc[r] = fmaf(w.x, f.x, acc[r]);
        acc[r] = fmaf(w.y, f.y, acc[r]);
        acc[r] = fmaf(w.z, f.z, acc[r]);
        acc[r] = fmaf(w.w, f.w, acc[r]);
      }
    }
    float s = 0.f, q = 0.f;
    #pragma unroll
    for (int r = 0; r < 8; r++) {
      fused[(size_t)(bk0 + rbase + r) * 128 + c] = acc[r];
      s += acc[r];
      q = fmaf(acc[r], acc[r], q);
    }
    const int prow = blockIdx.x * 2 + (t >> 7);
    part2[prow * 256 + c]       = s;
    part2[prow * 256 + 128 + c] = q;
  }
}

// ---------------------------------------------------------------------------
// E: out (local finalize2 + BN + relu). 128 blocks x 256 threads.
// ---------------------------------------------------------------------------
__global__ __launch_bounds__(256) void out_kernel(
    const float* __restrict__ fused, const float* __restrict__ part2,
    const float* __restrict__ gf, const float* __restrict__ bfp,
    float* __restrict__ out)
{
  __shared__ float sA[128], sB[128];
  __shared__ float tmp[2][128];
  const int t = threadIdx.x;
  {
    const int c = t & 127, which = t >> 7;
    float s = 0.f;
    for (int r = 0; r < 512; r++) s += part2[r * 256 + which * 128 + c];
    tmp[which][c] = s;
  }
  __syncthreads();
  if (t < 128) {
    const float mean = tmp[0][t] / MROW;
    const float var  = tmp[1][t] / MROW - mean * mean;
    const float A = gf[t] / sqrtf(var + 1e-5f);
    sA[t] = A;
    sB[t] = bfp[t] - mean * A;
  }
  __syncthreads();
  #pragma unroll
  for (int k = 0; k < 4; k++) {
    const int f4 = blockIdx.x * 1024 + k * 256 + t;   // 0..131071
    const int i = f4 * 4;
    const float4 v = *(const float4*)(fused + i);
    const int c = i & 127;
    float4 o;
    o.x = fmaxf(fmaf(v.x, sA[c+0], sB[c+0]), 0.f);
    o.y = fmaxf(fmaf(v.y, sA[c+1], sB[c+1]), 0.f);
    o.z = fmaxf(fmaf(v.z, sA[c+2], sB[c+2]), 0.f);
    o.w = fmaxf(fmaf(v.w, sA[c+3], sB[c+3]), 0.f);
    *(float4*)(out + i) = o;
  }
}

// ---------------------------------------------------------------------------
extern "C" void kernel_launch(void* const* d_in, const int* in_sizes, int n_in,
                              void* d_out, int out_size, void* d_ws, size_t ws_size,
                              hipStream_t stream)
{
  const float* kp    = (const float*)d_in[0];
  const float* pts   = (const float*)d_in[1];
  const float* pfeat = (const float*)d_in[2];
  const float* bev   = (const float*)d_in[3];
  const int*   strd  = (const int*)d_in[4];
  const float* W0s0  = (const float*)d_in[5];
  const float* g0s0  = (const float*)d_in[6];
  const float* b0s0  = (const float*)d_in[7];
  const float* W1s0  = (const float*)d_in[8];
  const float* g1s0  = (const float*)d_in[9];
  const float* b1s0  = (const float*)d_in[10];
  const float* W0s1  = (const float*)d_in[11];
  const float* g0s1  = (const float*)d_in[12];
  const float* b0s1  = (const float*)d_in[13];
  const float* W1s1  = (const float*)d_in[14];
  const float* g1s1  = (const float*)d_in[15];
  const float* b1s1  = (const float*)d_in[16];
  const float* Wf    = (const float*)d_in[17];
  const float* gf    = (const float*)d_in[18];
  const float* bfv   = (const float*)d_in[19];

  float* w      = (float*)d_ws;
  float* g0buf  = w;                        // 262144
  float* g1buf  = w + 262144;               // 262144
  float* feats  = w + 524288;               // 4096*304 = 1245184
  float* fused  = w + 1769472;              // 4096*128 = 524288
  float* part0  = w + 2293760;              // 64*28 (reserve 2048)
  float* part1  = w + 2295808;              // 256*96 = 24576
  float* part2  = w + 2320384;              // 512*256 = 131072
  int*   cnt       = (int*)(w + 2451456);   // 8192 ints
  int*   bin_start = (int*)(w + 2459648);   // 2*4416 (reserve 9216)
  int*   sidx      = (int*)(w + 2468864);   // 32768
  float4* sorted   = (float4*)(w + 2501632);// 32768 float4 (16B aligned)

  hipLaunchKernelGGL(prep_kernel,  dim3(514), dim3(256), 0, stream,
                     kp, pts, pfeat, bev, strd, bin_start, sorted, sidx, feats);
  hipLaunchKernelGGL(query_kernel, dim3(64), dim3(64), 0, stream,
                     kp, bin_start, sorted, sidx, g0buf, g1buf, cnt, part0);
  hipLaunchKernelGGL(stats1_kernel, dim3(256), dim3(256), 0, stream,
                     g0buf, g1buf, part0,
                     W0s0, g0s0, b0s0, W0s1, g0s1, b0s1, W1s0, W1s1, part1);
  hipLaunchKernelGGL(poolgemm_kernel, dim3(256), dim3(256), 0, stream,
                     g0buf, g1buf, cnt, part0, part1,
                     W0s0, g0s0, b0s0, W0s1, g0s1, b0s1,
                     W1s0, g1s0, b1s0, W1s1, g1s1, b1s1,
                     feats, Wf, fused, part2);
  hipLaunchKernelGGL(out_kernel,   dim3(128), dim3(256), 0, stream,
                     fused, part2, gf, bfv, (float*)d_out);
}